// Round 2
// baseline (1374.047 us; speedup 1.0000x reference)
//
#include <hip/hip_runtime.h>
#include <hip/hip_bf16.h>

#define DD 256          // node encoding dim
#define WAVE 64

// ---------------- mask handling ----------------
// jax bool may arrive as uint8 (1B) or int32 (4B). Detect: int32-stored 0/1
// words have zero bytes at positions i%4 != 0; uint8 bool (~80% ones) does not.
__global__ void detect_mask_kernel(const unsigned char* __restrict__ m, int nbytes,
                                   int* __restrict__ flag) {
    int i = blockIdx.x * blockDim.x + threadIdx.x;
    int stride = gridDim.x * blockDim.x;
    for (; i < nbytes; i += stride) {
        if ((i & 3) && m[i]) { *flag = 1; return; }
    }
}

__device__ __forceinline__ bool get_mask(const void* mp, int is8, int i) {
    if (is8) return ((const unsigned char*)mp)[i] != 0;
    return ((const int*)mp)[i] != 0;
}

// ---------------- CSR build ----------------
__global__ void count_kernel(const void* __restrict__ mask, const int* __restrict__ flag,
                             const int* __restrict__ idx, int* __restrict__ counts, int nocc) {
    int is8 = *flag;
    int i = blockIdx.x * blockDim.x + threadIdx.x;
    int stride = gridDim.x * blockDim.x;
    for (; i < nocc; i += stride) {
        if (get_mask(mask, is8, i)) atomicAdd(&counts[idx[i]], 1);
    }
}

// single-block exclusive scan over n counts -> offsets, cursor (copy)
__global__ void scan_kernel(const int* __restrict__ counts, int* __restrict__ offsets,
                            int* __restrict__ cursor, int n) {
    __shared__ int wsum[4];
    __shared__ int wexcl[4];
    __shared__ int running;
    __shared__ int chunk_total;
    int tid = threadIdx.x;
    if (tid == 0) running = 0;
    __syncthreads();
    for (int base = 0; base < n; base += 1024) {
        int i0 = base + tid * 4;
        int v[4];
        #pragma unroll
        for (int j = 0; j < 4; ++j) { int i = i0 + j; v[j] = (i < n) ? counts[i] : 0; }
        int tsum = v[0] + v[1] + v[2] + v[3];
        int lane = tid & 63, w = tid >> 6;
        int s = tsum;
        #pragma unroll
        for (int o = 1; o < 64; o <<= 1) { int t = __shfl_up(s, o, 64); if (lane >= o) s += t; }
        if (lane == 63) wsum[w] = s;
        __syncthreads();
        if (tid == 0) {
            int a = 0;
            #pragma unroll
            for (int j = 0; j < 4; ++j) { wexcl[j] = a; a += wsum[j]; }
            chunk_total = a;
        }
        __syncthreads();
        int tbase = running + wexcl[w] + (s - tsum);
        #pragma unroll
        for (int j = 0; j < 4; ++j) {
            int i = i0 + j;
            if (i < n) { offsets[i] = tbase; cursor[i] = tbase; }
            tbase += v[j];
        }
        __syncthreads();
        if (tid == 0) running += chunk_total;
        __syncthreads();
    }
}

__global__ void scatter_kernel(const void* __restrict__ mask, const int* __restrict__ flag,
                               const int* __restrict__ idx, int* __restrict__ cursor,
                               int* __restrict__ occ_list, int nocc) {
    int is8 = *flag;
    int i = blockIdx.x * blockDim.x + threadIdx.x;
    int stride = gridDim.x * blockDim.x;
    for (; i < nocc; i += stride) {
        if (get_mask(mask, is8, i)) {
            int p = atomicAdd(&cursor[idx[i]], 1);
            occ_list[p] = i;
        }
    }
}

// ---------------- q = prev @ Wq  (f32, LDS-tiled, 8x4 reg tile) ----------------
__global__ __launch_bounds__(256) void q_gemm_kernel(const float* __restrict__ A,
                                                     const float* __restrict__ W,
                                                     float* __restrict__ out, int M) {
    __shared__ float sA[32 * DD];
    int m0 = blockIdx.x * 32;
    int tid = threadIdx.x;
    for (int t = tid; t < 32 * DD; t += 256) {
        int r = t >> 8, k = t & 255;
        int gr = m0 + r;
        sA[t] = (gr < M) ? A[(size_t)gr * DD + k] : 0.f;
    }
    __syncthreads();
    int tx = tid & 63, ty = tid >> 6;
    float acc[8][4] = {};
    const float* A0 = &sA[ty * 8 * DD];
    #pragma unroll 4
    for (int k = 0; k < DD; ++k) {
        float4 wv = *(const float4*)(W + (size_t)k * DD + tx * 4);
        float a[8];
        #pragma unroll
        for (int i = 0; i < 8; ++i) a[i] = A0[i * DD + k];
        #pragma unroll
        for (int i = 0; i < 8; ++i) {
            acc[i][0] += a[i] * wv.x; acc[i][1] += a[i] * wv.y;
            acc[i][2] += a[i] * wv.z; acc[i][3] += a[i] * wv.w;
        }
    }
    #pragma unroll
    for (int i = 0; i < 8; ++i) {
        int gr = m0 + ty * 8 + i;
        if (gr < M)
            *(float4*)(out + (size_t)gr * DD + tx * 4) =
                make_float4(acc[i][0], acc[i][1], acc[i][2], acc[i][3]);
    }
}

// ---------------- node-centric fused score+softmax+aggregate ----------------
// one wave per node; agg[n] = sum_i exp(dot(enc_i, q_n)/16) * enc_i / (sum exp + 1e-9)
__global__ void node_agg_kernel(const float* __restrict__ enc, const float* __restrict__ q,
                                const int* __restrict__ offsets, const int* __restrict__ counts,
                                const int* __restrict__ occ_list, float* __restrict__ agg, int N) {
    int wid = blockIdx.x * (blockDim.x >> 6) + (threadIdx.x >> 6);
    if (wid >= N) return;
    int lane = threadIdx.x & 63;
    float4 qv = *(const float4*)(q + (size_t)wid * DD + lane * 4);
    int start = offsets[wid];
    int cnt = counts[wid];
    float4 acc = make_float4(0.f, 0.f, 0.f, 0.f);
    float denom = 0.f;
    for (int i = 0; i < cnt; ++i) {
        int occ = occ_list[start + i];
        float4 ev = *(const float4*)(enc + (size_t)occ * DD + lane * 4);
        float dp = ev.x * qv.x + ev.y * qv.y + ev.z * qv.z + ev.w * qv.w;
        #pragma unroll
        for (int o = 32; o > 0; o >>= 1) dp += __shfl_xor(dp, o, 64);
        float e = __expf(dp * 0.0625f);
        acc.x += e * ev.x; acc.y += e * ev.y; acc.z += e * ev.z; acc.w += e * ev.w;
        denom += e;
    }
    float inv = 1.0f / (denom + 1e-9f);
    *(float4*)(agg + (size_t)wid * DD + lane * 4) =
        make_float4(acc.x * inv, acc.y * inv, acc.z * inv, acc.w * inv);
}

// ---------------- gated update: out = z*prev + (1-z)*agg, z = sigmoid([prev;agg]@Wg + bg)
__global__ __launch_bounds__(256) void gate_gemm_kernel(const float* __restrict__ prev,
                                                        const float* __restrict__ agg,
                                                        const float* __restrict__ Wg,
                                                        const float* __restrict__ bg,
                                                        float* __restrict__ out, int M) {
    __shared__ float sP[32 * DD];
    __shared__ float sG[32 * DD];
    int m0 = blockIdx.x * 32;
    int tid = threadIdx.x;
    for (int t = tid; t < 32 * DD; t += 256) {
        int r = t >> 8, k = t & 255;
        int gr = m0 + r;
        sP[t] = (gr < M) ? prev[(size_t)gr * DD + k] : 0.f;
        sG[t] = (gr < M) ? agg[(size_t)gr * DD + k] : 0.f;
    }
    __syncthreads();
    int tx = tid & 63, ty = tid >> 6;
    float acc[8][4] = {};
    const float* P0 = &sP[ty * 8 * DD];
    const float* G0 = &sG[ty * 8 * DD];
    #pragma unroll 2
    for (int k = 0; k < DD; ++k) {
        float4 wv = *(const float4*)(Wg + (size_t)k * DD + tx * 4);
        float a[8];
        #pragma unroll
        for (int i = 0; i < 8; ++i) a[i] = P0[i * DD + k];
        #pragma unroll
        for (int i = 0; i < 8; ++i) {
            acc[i][0] += a[i] * wv.x; acc[i][1] += a[i] * wv.y;
            acc[i][2] += a[i] * wv.z; acc[i][3] += a[i] * wv.w;
        }
    }
    #pragma unroll 2
    for (int k = 0; k < DD; ++k) {
        float4 wv = *(const float4*)(Wg + (size_t)(DD + k) * DD + tx * 4);
        float a[8];
        #pragma unroll
        for (int i = 0; i < 8; ++i) a[i] = G0[i * DD + k];
        #pragma unroll
        for (int i = 0; i < 8; ++i) {
            acc[i][0] += a[i] * wv.x; acc[i][1] += a[i] * wv.y;
            acc[i][2] += a[i] * wv.z; acc[i][3] += a[i] * wv.w;
        }
    }
    float4 bgv = *(const float4*)(bg + tx * 4);
    float bga[4] = {bgv.x, bgv.y, bgv.z, bgv.w};
    #pragma unroll
    for (int i = 0; i < 8; ++i) {
        int gr = m0 + ty * 8 + i;
        if (gr >= M) continue;
        float r[4];
        #pragma unroll
        for (int j = 0; j < 4; ++j) {
            float zl = acc[i][j] + bga[j];
            float z = 1.f / (1.f + __expf(-zl));
            float pv = P0[i * DD + tx * 4 + j];
            float gv = G0[i * DD + tx * 4 + j];
            r[j] = z * pv + (1.f - z) * gv;
        }
        *(float4*)(out + (size_t)gr * DD + tx * 4) = make_float4(r[0], r[1], r[2], r[3]);
    }
}

extern "C" void kernel_launch(void* const* d_in, const int* in_sizes, int n_in,
                              void* d_out, int out_size, void* d_ws, size_t ws_size,
                              hipStream_t stream) {
    const float* enc  = (const float*)d_in[0];
    const void*  mask = d_in[1];
    const int*   idx  = (const int*)d_in[2];
    const float* prev = (const float*)d_in[3];
    const float* Wq   = (const float*)d_in[4];
    const float* Wg   = (const float*)d_in[5];
    const float* bg   = (const float*)d_in[6];
    float* out = (float*)d_out;

    const int nocc = in_sizes[2];          // N_PATHS * PATH_LEN
    const int N    = in_sizes[3] / DD;     // nr_cfg_nodes

    auto align256 = [](size_t x) { return (x + 255) & ~(size_t)255; };
    char* ws = (char*)d_ws;
    size_t off = 0;
    float* q       = (float*)(ws + off); off += align256((size_t)N * DD * 4);
    float* agg     = (float*)(ws + off); off += align256((size_t)N * DD * 4);
    int*   counts  = (int*)(ws + off);   off += align256((size_t)N * 4);
    int*   offsets = (int*)(ws + off);   off += align256((size_t)N * 4);
    int*   cursor  = (int*)(ws + off);   off += align256((size_t)N * 4);
    int*   occ_list= (int*)(ws + off);   off += align256((size_t)nocc * 4);
    int*   flag    = (int*)(ws + off);   off += 256;

    hipMemsetAsync(counts, 0, (size_t)N * 4, stream);
    hipMemsetAsync(flag, 0, 4, stream);

    detect_mask_kernel<<<256, 256, 0, stream>>>((const unsigned char*)mask, nocc, flag);
    count_kernel<<<1024, 256, 0, stream>>>(mask, flag, idx, counts, nocc);
    scan_kernel<<<1, 256, 0, stream>>>(counts, offsets, cursor, N);
    scatter_kernel<<<1024, 256, 0, stream>>>(mask, flag, idx, cursor, occ_list, nocc);
    q_gemm_kernel<<<(N + 31) / 32, 256, 0, stream>>>(prev, Wq, q, N);
    node_agg_kernel<<<(N + 3) / 4, 256, 0, stream>>>(enc, q, offsets, counts, occ_list, agg, N);
    gate_gemm_kernel<<<(N + 31) / 32, 256, 0, stream>>>(prev, agg, Wg, bg, out, N);
}

// Round 4
// 977.979 us; speedup vs baseline: 1.4050x; 1.4050x over previous
//
#include <hip/hip_runtime.h>
#include <hip/hip_bf16.h>

#define DD 256          // node encoding dim

typedef __attribute__((ext_vector_type(8))) short short8v;
typedef __attribute__((ext_vector_type(4))) float f32x4;
typedef __attribute__((ext_vector_type(4))) unsigned short ushort4v;

__device__ __forceinline__ unsigned short f2bf(float x) {
    __hip_bfloat16 h = __float2bfloat16(x);
    return __builtin_bit_cast(unsigned short, h);
}
__device__ __forceinline__ float bf2f(unsigned short u) {
    unsigned int ui = ((unsigned int)u) << 16;
    return __builtin_bit_cast(float, ui);
}

// ---------------- mask handling ----------------
// jax bool may arrive as uint8 (1B) or int32 (4B). Detect: int32-stored 0/1
// words have zero bytes at positions i%4 != 0; uint8 bool (~80% ones) does not.
__global__ void detect_mask_kernel(const unsigned char* __restrict__ m, int nbytes,
                                   int* __restrict__ flag) {
    int i = blockIdx.x * blockDim.x + threadIdx.x;
    int stride = gridDim.x * blockDim.x;
    for (; i < nbytes; i += stride) {
        if ((i & 3) && m[i]) { *flag = 1; return; }
    }
}

__device__ __forceinline__ bool get_mask(const void* mp, int is8, int i) {
    if (is8) return ((const unsigned char*)mp)[i] != 0;
    return ((const int*)mp)[i] != 0;
}

// ---------------- CSR build ----------------
__global__ void count_kernel(const void* __restrict__ mask, const int* __restrict__ flag,
                             const int* __restrict__ idx, int* __restrict__ counts, int nocc) {
    int is8 = *flag;
    int i = blockIdx.x * blockDim.x + threadIdx.x;
    int stride = gridDim.x * blockDim.x;
    for (; i < nocc; i += stride) {
        if (get_mask(mask, is8, i)) atomicAdd(&counts[idx[i]], 1);
    }
}

// 3-phase parallel exclusive scan (1024 elems per block in phase 1)
__global__ __launch_bounds__(256) void scan_part_kernel(const int* __restrict__ counts,
                                                        int* __restrict__ offsets,
                                                        int* __restrict__ bsums, int n) {
    __shared__ int wsum[4];
    __shared__ int wexcl[4];
    int tid = threadIdx.x;
    int i0 = blockIdx.x * 1024 + tid * 4;
    int v[4];
    #pragma unroll
    for (int j = 0; j < 4; ++j) { int i = i0 + j; v[j] = (i < n) ? counts[i] : 0; }
    int tsum = v[0] + v[1] + v[2] + v[3];
    int lane = tid & 63, w = tid >> 6;
    int s = tsum;
    #pragma unroll
    for (int o = 1; o < 64; o <<= 1) { int t = __shfl_up(s, o, 64); if (lane >= o) s += t; }
    if (lane == 63) wsum[w] = s;
    __syncthreads();
    if (tid == 0) {
        int a = 0;
        #pragma unroll
        for (int j = 0; j < 4; ++j) { wexcl[j] = a; a += wsum[j]; }
        bsums[blockIdx.x] = a;
    }
    __syncthreads();
    int tb = wexcl[w] + (s - tsum);
    #pragma unroll
    for (int j = 0; j < 4; ++j) {
        int i = i0 + j;
        if (i < n) offsets[i] = tb;
        tb += v[j];
    }
}

__global__ void scan_tops_kernel(int* __restrict__ bsums, int nb) {
    int l = threadIdx.x;   // 64 threads
    if (nb <= 64) {
        int v = (l < nb) ? bsums[l] : 0;
        int s = v;
        #pragma unroll
        for (int o = 1; o < 64; o <<= 1) { int t = __shfl_up(s, o, 64); if (l >= o) s += t; }
        if (l < nb) bsums[l] = s - v;
    } else if (l == 0) {
        int run = 0;
        for (int i = 0; i < nb; ++i) { int v = bsums[i]; bsums[i] = run; run += v; }
    }
}

__global__ void scan_add_kernel(int* __restrict__ offsets, const int* __restrict__ bsums,
                                int* __restrict__ cursor, int n) {
    int i = blockIdx.x * blockDim.x + threadIdx.x;
    if (i < n) {
        int o = offsets[i] + bsums[i >> 10];
        offsets[i] = o;
        cursor[i] = o;
    }
}

__global__ void scatter_kernel(const void* __restrict__ mask, const int* __restrict__ flag,
                               const int* __restrict__ idx, int* __restrict__ cursor,
                               int* __restrict__ occ_list, int nocc) {
    int is8 = *flag;
    int i = blockIdx.x * blockDim.x + threadIdx.x;
    int stride = gridDim.x * blockDim.x;
    for (; i < nocc; i += stride) {
        if (get_mask(mask, is8, i)) {
            int p = atomicAdd(&cursor[idx[i]], 1);
            occ_list[p] = i;
        }
    }
}

// ---------------- prep: f32 -> bf16 conversions ----------------
// prev [M][256] f32 -> [padM][256] bf16 (pad rows zeroed)
__global__ void convert_prev_kernel(const float* __restrict__ src, unsigned short* __restrict__ dst,
                                    int M, int padM) {
    int total = padM * (DD / 8);
    int i = blockIdx.x * blockDim.x + threadIdx.x;
    int stride = gridDim.x * blockDim.x;
    for (; i < total; i += stride) {
        int row = i >> 5;   // i / (DD/8)
        short8v vv;
        if (row < M) {
            const float* p = src + (size_t)i * 8;
            #pragma unroll
            for (int j = 0; j < 8; ++j) vv[j] = (short)f2bf(p[j]);
        } else {
            #pragma unroll
            for (int j = 0; j < 8; ++j) vv[j] = 0;
        }
        *(short8v*)(dst + (size_t)i * 8) = vv;
    }
}

// W [K][256] f32 -> WT [256][K] bf16 (transposed, n-major)
__global__ void wt_build_kernel(const float* __restrict__ W, unsigned short* __restrict__ WT, int K) {
    int n = blockIdx.x;   // 256 blocks
    for (int k = threadIdx.x; k < K; k += 256)
        WT[(size_t)n * K + k] = f2bf(W[(size_t)k * DD + n]);
}

// ---------------- q = prev @ Wq  (bf16 MFMA, no LDS) ----------------
// block = 256 thr = 4 waves; wave w: rows m0+w*32 .. +32, all 256 cols.
// Fragments loaded with identical (group,elem)->k mapping for A and B, so the
// result is invariant to the HW's internal k permutation.
__global__ __launch_bounds__(256) void q_gemm_mfma(const unsigned short* __restrict__ A,
                                                   const unsigned short* __restrict__ WT,
                                                   float* __restrict__ out, int M) {
    int w = threadIdx.x >> 6, l = threadIdx.x & 63;
    int r = l & 15, g = l >> 4;
    int mrow = blockIdx.x * 128 + w * 32;
    f32x4 acc[2][16];
    #pragma unroll
    for (int mi = 0; mi < 2; ++mi)
        #pragma unroll
        for (int ni = 0; ni < 16; ++ni) acc[mi][ni] = (f32x4){0.f, 0.f, 0.f, 0.f};
    const unsigned short* A0 = A + (size_t)(mrow + r) * DD;
    const unsigned short* A1 = A + (size_t)(mrow + 16 + r) * DD;
    for (int k0 = 0; k0 < DD; k0 += 32) {
        short8v a0 = *(const short8v*)(A0 + k0 + g * 8);
        short8v a1 = *(const short8v*)(A1 + k0 + g * 8);
        #pragma unroll
        for (int ni = 0; ni < 16; ++ni) {
            short8v b = *(const short8v*)(WT + (size_t)(ni * 16 + r) * DD + k0 + g * 8);
            acc[0][ni] = __builtin_amdgcn_mfma_f32_16x16x32_bf16(a0, b, acc[0][ni], 0, 0, 0);
            acc[1][ni] = __builtin_amdgcn_mfma_f32_16x16x32_bf16(a1, b, acc[1][ni], 0, 0, 0);
        }
    }
    // D layout: lane 16g+r holds rows 4g+j, col r of each 16x16 frag [m89-verified]
    #pragma unroll
    for (int mi = 0; mi < 2; ++mi)
        #pragma unroll
        for (int j = 0; j < 4; ++j) {
            int row = mrow + mi * 16 + g * 4 + j;
            if (row < M) {
                #pragma unroll
                for (int ni = 0; ni < 16; ++ni)
                    out[(size_t)row * DD + ni * 16 + r] = acc[mi][ni][j];
            }
        }
}

// ---------------- node-centric fused score+softmax+aggregate ----------------
// one wave per node; agg[n] = sum_i exp(dot(enc_i, q_n)/16) * enc_i / (sum exp + 1e-9)
__global__ void node_agg_kernel(const float* __restrict__ enc, const float* __restrict__ q,
                                const int* __restrict__ offsets, const int* __restrict__ counts,
                                const int* __restrict__ occ_list,
                                unsigned short* __restrict__ aggb, int N) {
    int wid = blockIdx.x * (blockDim.x >> 6) + (threadIdx.x >> 6);
    if (wid >= N) return;
    int lane = threadIdx.x & 63;
    float4 qv = *(const float4*)(q + (size_t)wid * DD + lane * 4);
    int start = offsets[wid];
    int cnt = counts[wid];
    float4 acc = make_float4(0.f, 0.f, 0.f, 0.f);
    float denom = 0.f;
    for (int i = 0; i < cnt; ++i) {
        int occ = occ_list[start + i];
        float4 ev = *(const float4*)(enc + (size_t)occ * DD + lane * 4);
        float dp = ev.x * qv.x + ev.y * qv.y + ev.z * qv.z + ev.w * qv.w;
        #pragma unroll
        for (int o = 32; o > 0; o >>= 1) dp += __shfl_xor(dp, o, 64);
        float e = __expf(dp * 0.0625f);
        acc.x += e * ev.x; acc.y += e * ev.y; acc.z += e * ev.z; acc.w += e * ev.w;
        denom += e;
    }
    float inv = 1.0f / (denom + 1e-9f);
    ushort4v o;
    o[0] = f2bf(acc.x * inv); o[1] = f2bf(acc.y * inv);
    o[2] = f2bf(acc.z * inv); o[3] = f2bf(acc.w * inv);
    *(ushort4v*)(aggb + (size_t)wid * DD + lane * 4) = o;
}

// ---------------- gate: logits=[prev;agg]@Wg+bg; out = z*prev+(1-z)*agg ----------------
__global__ __launch_bounds__(256) void gate_gemm_mfma(const unsigned short* __restrict__ Ap,
                                                      const unsigned short* __restrict__ Ag,
                                                      const unsigned short* __restrict__ WT,
                                                      const float* __restrict__ prev,
                                                      const float* __restrict__ bg,
                                                      float* __restrict__ out, int M) {
    int w = threadIdx.x >> 6, l = threadIdx.x & 63;
    int r = l & 15, g = l >> 4;
    int mrow = blockIdx.x * 128 + w * 32;
    f32x4 acc[2][16];
    #pragma unroll
    for (int mi = 0; mi < 2; ++mi)
        #pragma unroll
        for (int ni = 0; ni < 16; ++ni) acc[mi][ni] = (f32x4){0.f, 0.f, 0.f, 0.f};
    const unsigned short* P0 = Ap + (size_t)(mrow + r) * DD;
    const unsigned short* P1 = Ap + (size_t)(mrow + 16 + r) * DD;
    for (int k0 = 0; k0 < DD; k0 += 32) {
        short8v a0 = *(const short8v*)(P0 + k0 + g * 8);
        short8v a1 = *(const short8v*)(P1 + k0 + g * 8);
        #pragma unroll
        for (int ni = 0; ni < 16; ++ni) {
            short8v b = *(const short8v*)(WT + (size_t)(ni * 16 + r) * 512 + k0 + g * 8);
            acc[0][ni] = __builtin_amdgcn_mfma_f32_16x16x32_bf16(a0, b, acc[0][ni], 0, 0, 0);
            acc[1][ni] = __builtin_amdgcn_mfma_f32_16x16x32_bf16(a1, b, acc[1][ni], 0, 0, 0);
        }
    }
    const unsigned short* G0 = Ag + (size_t)(mrow + r) * DD;
    const unsigned short* G1 = Ag + (size_t)(mrow + 16 + r) * DD;
    for (int k0 = 0; k0 < DD; k0 += 32) {
        short8v a0 = *(const short8v*)(G0 + k0 + g * 8);
        short8v a1 = *(const short8v*)(G1 + k0 + g * 8);
        #pragma unroll
        for (int ni = 0; ni < 16; ++ni) {
            short8v b = *(const short8v*)(WT + (size_t)(ni * 16 + r) * 512 + 256 + k0 + g * 8);
            acc[0][ni] = __builtin_amdgcn_mfma_f32_16x16x32_bf16(a0, b, acc[0][ni], 0, 0, 0);
            acc[1][ni] = __builtin_amdgcn_mfma_f32_16x16x32_bf16(a1, b, acc[1][ni], 0, 0, 0);
        }
    }
    float bgc[16];
    #pragma unroll
    for (int ni = 0; ni < 16; ++ni) bgc[ni] = bg[ni * 16 + r];
    const unsigned short* aggb = Ag;
    #pragma unroll
    for (int mi = 0; mi < 2; ++mi)
        #pragma unroll
        for (int j = 0; j < 4; ++j) {
            int row = mrow + mi * 16 + g * 4 + j;
            if (row < M) {
                #pragma unroll
                for (int ni = 0; ni < 16; ++ni) {
                    int col = ni * 16 + r;
                    float zl = acc[mi][ni][j] + bgc[ni];
                    float z = 1.f / (1.f + __expf(-zl));
                    float pv = prev[(size_t)row * DD + col];
                    float av = bf2f(aggb[(size_t)row * DD + col]);
                    out[(size_t)row * DD + col] = z * pv + (1.f - z) * av;
                }
            }
        }
}

extern "C" void kernel_launch(void* const* d_in, const int* in_sizes, int n_in,
                              void* d_out, int out_size, void* d_ws, size_t ws_size,
                              hipStream_t stream) {
    const float* enc  = (const float*)d_in[0];
    const void*  mask = d_in[1];
    const int*   idx  = (const int*)d_in[2];
    const float* prev = (const float*)d_in[3];
    const float* Wq   = (const float*)d_in[4];
    const float* Wg   = (const float*)d_in[5];
    const float* bg   = (const float*)d_in[6];
    float* out = (float*)d_out;

    const int nocc = in_sizes[2];          // N_PATHS * PATH_LEN
    const int N    = in_sizes[3] / DD;     // nr_cfg_nodes
    const int padM = (N + 127) & ~127;

    auto align256 = [](size_t x) { return (x + 255) & ~(size_t)255; };
    char* ws = (char*)d_ws;
    size_t off = 0;
    unsigned short* prevb = (unsigned short*)(ws + off); off += align256((size_t)padM * DD * 2);
    unsigned short* aggb  = (unsigned short*)(ws + off); off += align256((size_t)padM * DD * 2);
    float* q        = (float*)(ws + off); off += align256((size_t)N * DD * 4);
    unsigned short* WTq = (unsigned short*)(ws + off); off += align256((size_t)DD * DD * 2);
    unsigned short* WTg = (unsigned short*)(ws + off); off += align256((size_t)DD * 512 * 2);
    int* counts  = (int*)(ws + off); off += align256((size_t)N * 4);
    int* offsets = (int*)(ws + off); off += align256((size_t)N * 4);
    int* cursor  = (int*)(ws + off); off += align256((size_t)N * 4);
    int* occ_list = (int*)(ws + off); off += align256((size_t)nocc * 4);
    int* bsums   = (int*)(ws + off); off += align256(1024 * 4);
    int* flag    = (int*)(ws + off); off += 256;

    const int nb = (N + 1023) / 1024;

    hipMemsetAsync(counts, 0, (size_t)N * 4, stream);
    hipMemsetAsync(flag, 0, 4, stream);

    detect_mask_kernel<<<256, 256, 0, stream>>>((const unsigned char*)mask, nocc, flag);
    count_kernel<<<1024, 256, 0, stream>>>(mask, flag, idx, counts, nocc);
    scan_part_kernel<<<nb, 256, 0, stream>>>(counts, offsets, bsums, N);
    scan_tops_kernel<<<1, 64, 0, stream>>>(bsums, nb);
    scan_add_kernel<<<(N + 255) / 256, 256, 0, stream>>>(offsets, bsums, cursor, N);
    scatter_kernel<<<1024, 256, 0, stream>>>(mask, flag, idx, cursor, occ_list, nocc);
    wt_build_kernel<<<256, 256, 0, stream>>>(Wq, WTq, DD);
    wt_build_kernel<<<256, 256, 0, stream>>>(Wg, WTg, 512);
    convert_prev_kernel<<<2048, 256, 0, stream>>>(prev, prevb, N, padM);
    q_gemm_mfma<<<padM / 128, 256, 0, stream>>>(prevb, WTq, q, N);
    node_agg_kernel<<<(N + 3) / 4, 256, 0, stream>>>(enc, q, offsets, counts, occ_list, aggb, N);
    gate_gemm_mfma<<<padM / 128, 256, 0, stream>>>(prevb, aggb, WTg, prev, bg, out, N);
}